// Round 13
// baseline (174.558 us; speedup 1.0000x reference)
//
#include <hip/hip_runtime.h>

#define N_NODES 65536
#define N_EDGES 1048576
#define B_GRAPHS 32
#define NPG     2048
#define EPS_GN  1e-5f
#define SLOPE   0.01f
#define NBUCKET 512     // buckets of 128 nodes (dst>>7)
#define STRIDE_B 2432   // fixed per-bucket capacity (mean 2048, sigma~45, ~8.5 sigma)
#define PLANE   ((size_t)N_NODES * 32)   // ushorts per 4-MB feature plane

typedef unsigned short ushort_t;
typedef unsigned int uint_t;

static __device__ __forceinline__ ushort_t f2bf(float f) {
    uint_t u = __float_as_uint(f);
    return (ushort_t)((u + 0x7FFFu + ((u >> 16) & 1u)) >> 16);
}

// accumulate 4 bf16 (one uint2) with weight w
static __device__ __forceinline__ void acc_bf4(float4& a, uint2 u, float w) {
    a.x += __uint_as_float(u.x << 16) * w;
    a.y += __uint_as_float(u.x & 0xffff0000u) * w;
    a.z += __uint_as_float(u.y << 16) * w;
    a.w += __uint_as_float(u.y & 0xffff0000u) * w;
}

// ---------------- src histogram (byte-packed LDS bins); block 0 inits cursor+done ----
__global__ __launch_bounds__(256) void hist_kernel(const int4* __restrict__ src4,
                                                   unsigned int* __restrict__ partial,
                                                   int* __restrict__ cursor,
                                                   int* __restrict__ done) {
    __shared__ unsigned int bins[16384];   // 64 KB
    int tid = threadIdx.x, c = blockIdx.x;
#pragma unroll
    for (int k = 0; k < 64; ++k) bins[k * 256 + tid] = 0u;
    if (c == 0) {
        cursor[tid] = tid * STRIDE_B;
        cursor[256 + tid] = (256 + tid) * STRIDE_B;
        if (tid < 2) done[tid] = 0;
    }
    __syncthreads();
#pragma unroll
    for (int k = 0; k < 16; ++k) {
        int4 v = src4[c * 4096 + k * 256 + tid];
        atomicAdd(&bins[v.x >> 2], 1u << ((v.x & 3) * 8));
        atomicAdd(&bins[v.y >> 2], 1u << ((v.y & 3) * 8));
        atomicAdd(&bins[v.z >> 2], 1u << ((v.z & 3) * 8));
        atomicAdd(&bins[v.w >> 2], 1u << ((v.w & 3) * 8));
    }
    __syncthreads();
    unsigned int* dstp = partial + c * 16384;
#pragma unroll
    for (int k = 0; k < 64; ++k) dstp[k * 256 + tid] = bins[k * 256 + tid];
}

// ---------------- reduce byte-counters over 64 chunks -> inv_so ----------------
__global__ __launch_bounds__(256) void reduce_src(const unsigned int* __restrict__ partial,
                                                  float4* __restrict__ inv_so4) {
    int w = blockIdx.x * 256 + threadIdx.x;   // grid 64
    unsigned int s0 = 0, s1 = 0, s2 = 0, s3 = 0;
#pragma unroll
    for (int c = 0; c < 64; ++c) {
        unsigned int v = partial[c * 16384 + w];
        s0 += v & 255u; s1 += (v >> 8) & 255u; s2 += (v >> 16) & 255u; s3 += v >> 24;
    }
    float4 r;
    r.x = rsqrtf((float)max((int)s0, 1));
    r.y = rsqrtf((float)max((int)s1, 1));
    r.z = rsqrtf((float)max((int)s2, 1));
    r.w = rsqrtf((float)max((int)s3, 1));
    inv_so4[w] = r;
}

// ---------------- bucket scatter: 256 blocks x 4096-edge chunks, 512 fixed-stride buckets ----
__global__ __launch_bounds__(256) void bucket_scatter(const int4* __restrict__ src4,
                                                      const int4* __restrict__ dst4,
                                                      const float4* __restrict__ ew4,
                                                      int* __restrict__ cursor,
                                                      int2* __restrict__ bedges) {
    __shared__ int lhist[NBUCKET];
    __shared__ int lstart[NBUCKET];
    __shared__ int gbase[NBUCKET];
    __shared__ int scA[256], scB[256];
    __shared__ int2 staged[4096];   // 32 KB
    int tid = threadIdx.x;
    int vbase = blockIdx.x * 1024;  // 4096 edges = 1024 int4
    lhist[tid] = 0;
    lhist[tid + 256] = 0;
    __syncthreads();
    int w0[16]; int wbr[16]; float wwt[16];
#pragma unroll
    for (int k = 0; k < 4; ++k) {
        int4 s = src4[vbase + k * 256 + tid];
        int4 d = dst4[vbase + k * 256 + tid];
        float4 w = ew4[vbase + k * 256 + tid];
        int ss[4] = {s.x, s.y, s.z, s.w};
        int dd[4] = {d.x, d.y, d.z, d.w};
        float wf[4] = {w.x, w.y, w.z, w.w};
#pragma unroll
        for (int j = 0; j < 4; ++j) {
            int b = dd[j] >> 7;
            w0[k * 4 + j] = ss[j] | ((dd[j] & 127) << 16);
            wwt[k * 4 + j] = wf[j];
            int r = atomicAdd(&lhist[b], 1);
            wbr[k * 4 + j] = (b << 16) | r;
        }
    }
    __syncthreads();
    int cntA = lhist[tid], cntB = lhist[tid + 256];
    scA[tid] = cntA;
    scB[tid] = cntB;
    __syncthreads();
    for (int off = 1; off < 256; off <<= 1) {
        int tA = (tid >= off) ? scA[tid - off] : 0;
        int tB = (tid >= off) ? scB[tid - off] : 0;
        __syncthreads();
        scA[tid] += tA;
        scB[tid] += tB;
        __syncthreads();
    }
    int lowtot = scA[255];
    lstart[tid] = scA[tid] - cntA;
    lstart[tid + 256] = lowtot + scB[tid] - cntB;
    gbase[tid] = cntA ? atomicAdd(&cursor[tid], cntA) : 0;
    gbase[tid + 256] = cntB ? atomicAdd(&cursor[tid + 256], cntB) : 0;
    __syncthreads();
#pragma unroll
    for (int k = 0; k < 16; ++k)
        staged[lstart[wbr[k] >> 16] + (wbr[k] & 0xFFFF)] =
            make_int2(w0[k], __float_as_int(wwt[k]));
    __syncthreads();
    {
        int gb = gbase[tid], ls = lstart[tid];
        for (int i = 0; i < cntA; ++i) bedges[gb + i] = staged[ls + i];
        gb = gbase[tid + 256]; ls = lstart[tid + 256];
        for (int i = 0; i < cntB; ++i) bedges[gb + i] = staged[ls + i];
    }
}

// ---------------- refine_lite: per-bucket node histogram -> nstart/ndeg ----------------
__global__ __launch_bounds__(256) void refine_lite(const int* __restrict__ bedges_x,
                                                   const int* __restrict__ cursor,
                                                   int* __restrict__ nstart,
                                                   int* __restrict__ ndeg) {
    __shared__ int hist[128], sc[128];
    int tid = threadIdx.x, b = blockIdx.x;   // grid 512
    int e0 = b * STRIDE_B;
    int nE = cursor[b] - e0;
    if (tid < 128) hist[tid] = 0;
    __syncthreads();
    for (int i = tid; i < nE; i += 256)
        atomicAdd(&hist[(bedges_x[2 * (e0 + i)] >> 16) & 127], 1);
    __syncthreads();
    if (tid < 128) sc[tid] = hist[tid];
    __syncthreads();
    for (int off = 1; off < 128; off <<= 1) {
        int t = (tid >= off && tid < 128) ? sc[tid - off] : 0;
        __syncthreads();
        if (tid < 128) sc[tid] += t;
        __syncthreads();
    }
    if (tid < 128) {
        int cnt = hist[tid];
        nstart[b * 128 + tid] = sc[tid] - cnt;
        ndeg[b * 128 + tid] = cnt;
    }
}

// ---------------- gemm (fp32 input, layer 1), 64 rows/block, plane-split output ----------
__global__ __launch_bounds__(256) void gemm_f32(const float* __restrict__ in,
                                                const float* __restrict__ W,
                                                const float* __restrict__ inv_so,
                                                ushort_t* __restrict__ out_bf) {
    __shared__ float wT[64][68];
    __shared__ float xlds[64][64];
    int tid = threadIdx.x;
#pragma unroll
    for (int j = 0; j < 16; ++j) {
        int i = j * 256 + tid;
        wT[i & 63][i >> 6] = W[i];
    }
    int r0 = blockIdx.x * 64;
#pragma unroll
    for (int j = 0; j < 16; ++j) {
        int i = j * 256 + tid;
        int r = i >> 6, k = i & 63;
        int gr = r0 + r;
        xlds[r][k] = in[(size_t)gr * 64 + k] * inv_so[gr];
    }
    __syncthreads();
    int c = tid & 63;
    int rg = tid >> 6;
    ushort_t* outp = out_bf + (size_t)(c >> 5) * PLANE + (c & 31);
    float acc[16];
#pragma unroll
    for (int j = 0; j < 16; ++j) acc[j] = 0.f;
#pragma unroll
    for (int k0 = 0; k0 < 64; k0 += 4) {
        float4 wv = *(const float4*)&wT[c][k0];
#pragma unroll
        for (int j = 0; j < 16; ++j) {
            float4 xv = *(const float4*)&xlds[rg * 16 + j][k0];
            acc[j] += xv.x * wv.x + xv.y * wv.y + xv.z * wv.z + xv.w * wv.w;
        }
    }
#pragma unroll
    for (int j = 0; j < 16; ++j)
        outp[(size_t)(r0 + rg * 16 + j) * 32] = f2bf(acc[j]);
}

// ---------------- gemm (bf16 plane input, layer 2): GN1 affine fused ----------------
__global__ __launch_bounds__(256) void gemm_bf16(const ushort_t* __restrict__ in,
                                                 const float* __restrict__ W,
                                                 const float* __restrict__ inv_so,
                                                 const float* __restrict__ alpha,
                                                 const float* __restrict__ beta,
                                                 ushort_t* __restrict__ out_bf) {
    __shared__ float wT[64][68];
    __shared__ float xlds[64][64];
    int tid = threadIdx.x;
#pragma unroll
    for (int j = 0; j < 16; ++j) {
        int i = j * 256 + tid;
        wT[i & 63][i >> 6] = W[i];
    }
    int r0 = blockIdx.x * 64;
    const uint_t* inU = (const uint_t*)in;   // plane rows: 16 uints each
#pragma unroll
    for (int j = 0; j < 8; ++j) {
        int idx = j * 256 + tid;            // 0..2047 = 64 rows x 32 uints
        int r = idx >> 5, kp = idx & 31;
        int gr = r0 + r;
        int pl = kp >> 4, kw = kp & 15;
        uint_t u = inU[(size_t)pl * (PLANE / 2) + (size_t)gr * 16 + kw];
        int k0 = pl * 32 + kw * 2;
        float lo = __uint_as_float(u << 16);
        float hi = __uint_as_float(u & 0xffff0000u);
        float iso = inv_so[gr];
        xlds[r][k0]     = (alpha[k0] * lo + beta[k0]) * iso;
        xlds[r][k0 + 1] = (alpha[k0 + 1] * hi + beta[k0 + 1]) * iso;
    }
    __syncthreads();
    int c = tid & 63;
    int rg = tid >> 6;
    ushort_t* outp = out_bf + (size_t)(c >> 5) * PLANE + (c & 31);
    float acc[16];
#pragma unroll
    for (int j = 0; j < 16; ++j) acc[j] = 0.f;
#pragma unroll
    for (int k0 = 0; k0 < 64; k0 += 4) {
        float4 wv = *(const float4*)&wT[c][k0];
#pragma unroll
        for (int j = 0; j < 16; ++j) {
            float4 xv = *(const float4*)&xlds[rg * 16 + j][k0];
            acc[j] += xv.x * wv.x + xv.y * wv.y + xv.z * wv.z + xv.w * wv.w;
        }
    }
#pragma unroll
    for (int j = 0; j < 16; ++j)
        outp[(size_t)(r0 + rg * 16 + j) * 32] = f2bf(acc[j]);
}

// ---------------- agg: LDS sort + two L2-resident gather passes (4-MB plane each) ----------
__global__ __launch_bounds__(1024, 8) void agg_bucket(const ushort_t* __restrict__ Tb,
                                                      const int2* __restrict__ bedges,
                                                      const int* __restrict__ cursor,
                                                      const int* __restrict__ nstart,
                                                      const int* __restrict__ ndeg,
                                                      ushort_t* __restrict__ Yb,   // nullable
                                                      float4* __restrict__ statsP4) {
    __shared__ int2 sorted[STRIDE_B];   // 19 KB
    __shared__ int nst[128], ndg[128], scur[128];
    int tid = threadIdx.x, b = blockIdx.x;
    int e0 = b * STRIDE_B;
    int nE = cursor[b] - e0;
    if (tid < 128) {
        int st = nstart[b * 128 + tid];
        nst[tid] = st;
        scur[tid] = st;
        ndg[tid] = ndeg[b * 128 + tid];
    }
    __syncthreads();
    for (int i = tid; i < nE; i += 1024) {
        int2 e = bedges[e0 + i];
        int dl = (e.x >> 16) & 127;
        int pos = atomicAdd(&scur[dl], 1);
        sorted[pos] = make_int2(e.x & 0xFFFF, e.y);
    }
    __syncthreads();
    const long* sl = (const long*)sorted;
    int l8 = tid & 7;
    int nl = tid >> 3;                 // 0..127
    int node = b * 128 + nl;
    int off = nst[nl];
    int cnt = ndg[nl];
    float4 vA, vB;
    // two passes: plane 0 (feats l8*4..+3), plane 1 (feats 32+l8*4..+3)
#pragma unroll
    for (int pass = 0; pass < 2; ++pass) {
        const ushort_t* Tp = Tb + (size_t)pass * PLANE;
        float4 a = make_float4(0.f, 0.f, 0.f, 0.f);
        int i = 0;
        for (; i + 8 <= cnt; i += 8) {
            long e[8];
#pragma unroll
            for (int k = 0; k < 8; ++k) e[k] = sl[off + i + k];
            uint2 t[8];
#pragma unroll
            for (int k = 0; k < 8; ++k)
                t[k] = ((const uint2*)(Tp + (((size_t)(e[k] & 0xFFFF)) << 5)))[l8];
#pragma unroll
            for (int k = 0; k < 8; ++k)
                acc_bf4(a, t[k], __int_as_float((int)(e[k] >> 32)));
        }
        for (; i < cnt; ++i) {
            long e = sl[off + i];
            uint2 u = ((const uint2*)(Tp + (((size_t)(e & 0xFFFF)) << 5)))[l8];
            acc_bf4(a, u, __int_as_float((int)(e >> 32)));
        }
        if (pass == 0) vA = a; else vB = a;
        __syncthreads();   // keep block's waves phase-aligned across planes
    }
    float s = rsqrtf((float)max(cnt, 1));
    vA.x *= s; vA.x = (vA.x >= 0.f) ? vA.x : SLOPE * vA.x;
    vA.y *= s; vA.y = (vA.y >= 0.f) ? vA.y : SLOPE * vA.y;
    vA.z *= s; vA.z = (vA.z >= 0.f) ? vA.z : SLOPE * vA.z;
    vA.w *= s; vA.w = (vA.w >= 0.f) ? vA.w : SLOPE * vA.w;
    vB.x *= s; vB.x = (vB.x >= 0.f) ? vB.x : SLOPE * vB.x;
    vB.y *= s; vB.y = (vB.y >= 0.f) ? vB.y : SLOPE * vB.y;
    vB.z *= s; vB.z = (vB.z >= 0.f) ? vB.z : SLOPE * vB.z;
    vB.w *= s; vB.w = (vB.w >= 0.f) ? vB.w : SLOPE * vB.w;
    if (Yb) {
        uint2 pa, pb;
        pa.x = (uint_t)f2bf(vA.x) | ((uint_t)f2bf(vA.y) << 16);
        pa.y = (uint_t)f2bf(vA.z) | ((uint_t)f2bf(vA.w) << 16);
        pb.x = (uint_t)f2bf(vB.x) | ((uint_t)f2bf(vB.y) << 16);
        pb.y = (uint_t)f2bf(vB.z) | ((uint_t)f2bf(vB.w) << 16);
        ((uint2*)(Yb + ((size_t)node << 5)))[l8] = pa;
        ((uint2*)(Yb + PLANE + ((size_t)node << 5)))[l8] = pb;
    }
    // per-wave stats partials via shfl (8 node-slots per wave)
    float4 s0 = vA, s1 = vB;
    float4 q0 = make_float4(vA.x * vA.x, vA.y * vA.y, vA.z * vA.z, vA.w * vA.w);
    float4 q1 = make_float4(vB.x * vB.x, vB.y * vB.y, vB.z * vB.z, vB.w * vB.w);
#pragma unroll
    for (int m = 8; m <= 32; m <<= 1) {
        s0.x += __shfl_xor(s0.x, m); s0.y += __shfl_xor(s0.y, m);
        s0.z += __shfl_xor(s0.z, m); s0.w += __shfl_xor(s0.w, m);
        s1.x += __shfl_xor(s1.x, m); s1.y += __shfl_xor(s1.y, m);
        s1.z += __shfl_xor(s1.z, m); s1.w += __shfl_xor(s1.w, m);
        q0.x += __shfl_xor(q0.x, m); q0.y += __shfl_xor(q0.y, m);
        q0.z += __shfl_xor(q0.z, m); q0.w += __shfl_xor(q0.w, m);
        q1.x += __shfl_xor(q1.x, m); q1.y += __shfl_xor(q1.y, m);
        q1.z += __shfl_xor(q1.z, m); q1.w += __shfl_xor(q1.w, m);
    }
    int wv = tid >> 6, ln = tid & 63;
    if (ln < 8) {
        // feats: s0 -> slot l8 (feats 4*l8..+3), s1 -> slot 8+l8 (feats 32+4*l8..+3)
        float4* row = statsP4 + ((size_t)b * 16 + wv) * 32;
        row[ln] = s0;
        row[8 + ln] = s1;
        row[16 + ln] = q0;
        row[24 + ln] = q1;
    }
}

// ---------------- reduce statsP -> slab; LAST block computes GN1 alpha/beta ----------------
__global__ __launch_bounds__(256) void reduce_finalize1(const float* __restrict__ statsP,
                                                        float* __restrict__ slab,
                                                        const float* __restrict__ w,
                                                        const float* __restrict__ bb,
                                                        const float* __restrict__ a,
                                                        float* __restrict__ alpha,
                                                        float* __restrict__ beta,
                                                        int* __restrict__ done) {
    __shared__ float red[256];
    __shared__ int isLast;
    int tid = threadIdx.x, b = blockIdx.x;   // grid 64
    int col = tid & 127, half = tid >> 7;
    float s = 0.f;
    for (int i = half; i < 128; i += 2)
        s += statsP[(size_t)(b * 128 + i) * 128 + col];
    red[tid] = s;
    __syncthreads();
    if (tid < 128) slab[b * 128 + tid] = red[tid] + red[tid + 128];
    __threadfence();
    if (tid == 0) isLast = (atomicAdd(done, 1) == 63);
    __syncthreads();
    if (isLast && tid < 64) {
        float Sy = 0.f, Qy = 0.f;
        for (int i = 0; i < 64; ++i) {
            Sy += slab[i * 128 + tid];
            Qy += slab[i * 128 + 64 + tid];
        }
        float m = Sy * (1.f / N_NODES);
        float q = Qy * (1.f / N_NODES);
        float af = a[tid];
        float var = q - 2.f * af * m * m + af * af * m * m;
        float al = w[tid] / sqrtf(var + EPS_GN);
        alpha[tid] = al;
        beta[tid] = bb[tid] - al * af * m;
    }
}

// ---------------- layer-2 reduce (stats + pool); LAST block does GN2 + pooled @ Wc^T ------
__global__ __launch_bounds__(256) void reduce_out2(const float* __restrict__ statsP,
                                                   float* __restrict__ slab,
                                                   float* __restrict__ pooledSum,
                                                   const float* __restrict__ gn_w,
                                                   const float* __restrict__ gn_b,
                                                   const float* __restrict__ gn_a,
                                                   const float* __restrict__ Wc,
                                                   float* __restrict__ out,
                                                   int* __restrict__ done) {
    __shared__ float red[256];
    __shared__ int isLast;
    int tid = threadIdx.x, b = blockIdx.x;   // grid 96
    if (b < 64) {
        int col = tid & 127, half = tid >> 7;
        float s = 0.f;
        for (int i = half; i < 128; i += 2)
            s += statsP[(size_t)(b * 128 + i) * 128 + col];
        red[tid] = s;
        __syncthreads();
        if (tid < 128) slab[b * 128 + tid] = red[tid] + red[tid + 128];
    } else {
        int g = b - 64;
        int col = tid & 63, part = tid >> 6;
        float s = 0.f;
        for (int r = g * 256 + part; r < (g + 1) * 256; r += 4)
            s += statsP[(size_t)r * 128 + col];
        red[tid] = s;
        __syncthreads();
        if (tid < 64)
            pooledSum[g * 64 + tid] =
                red[tid] + red[tid + 64] + red[tid + 128] + red[tid + 192];
    }
    __threadfence();
    if (tid == 0) isLast = (atomicAdd(done, 1) == 95);
    __syncthreads();
    if (!isLast) return;
    __shared__ float al[64], be[64];
    __shared__ float p[B_GRAPHS * 64];
    if (tid < 64) {
        float Sy = 0.f, Qy = 0.f;
        for (int i = 0; i < 64; ++i) {
            Sy += slab[i * 128 + tid];
            Qy += slab[i * 128 + 64 + tid];
        }
        float m = Sy * (1.f / N_NODES);
        float q = Qy * (1.f / N_NODES);
        float af = gn_a[tid];
        float var = q - 2.f * af * m * m + af * af * m * m;
        float a_ = gn_w[tid] / sqrtf(var + EPS_GN);
        al[tid] = a_;
        be[tid] = gn_b[tid] - a_ * af * m;
    }
    __syncthreads();
    for (int i = tid; i < B_GRAPHS * 64; i += 256) {
        int f = i & 63;
        p[i] = al[f] * (pooledSum[i] * (1.f / NPG)) + be[f];
    }
    __syncthreads();
    for (int idx = tid; idx < B_GRAPHS * 32; idx += 256) {
        int g = idx >> 5, o = idx & 31;
        float acc = 0.f;
        for (int f = 0; f < 64; ++f)
            acc += p[g * 64 + f] * Wc[o * 64 + f];
        out[idx] = acc;
    }
}

extern "C" void kernel_launch(void* const* d_in, const int* in_sizes, int n_in,
                              void* d_out, int out_size, void* d_ws, size_t ws_size,
                              hipStream_t stream) {
    const float* x     = (const float*)d_in[0];
    const float* ew    = (const float*)d_in[1];
    const float* W1    = (const float*)d_in[2];
    const float* W2    = (const float*)d_in[3];
    const float* Wc    = (const float*)d_in[4];
    const float* gn1_w = (const float*)d_in[5];
    const float* gn1_b = (const float*)d_in[6];
    const float* gn1_a = (const float*)d_in[7];
    const float* gn2_w = (const float*)d_in[8];
    const float* gn2_b = (const float*)d_in[9];
    const float* gn2_a = (const float*)d_in[10];
    const int* src     = (const int*)d_in[11];
    const int* dst     = (const int*)d_in[12];

    char* ws = (char*)d_ws;
    int*   cursor    = (int*)(ws + 0);              // 2 KB (512 ints)
    int*   done      = (int*)(ws + 2048);           // 2 ints
    float* ab1       = (float*)(ws + 4096);         // 512 B
    float* pooledSum = (float*)(ws + 8192);         // 8 KB
    float* slab1     = (float*)(ws + 16384);        // 32 KB
    float* slab2     = (float*)(ws + 49152);        // 32 KB
    int*   nstart    = (int*)(ws + 131072);         // 256 KB
    int*   ndeg      = (int*)(ws + 393216);         // 256 KB
    float* inv_so    = (float*)(ws + 655360);       // 256 KB
    unsigned int* partial = (unsigned int*)(ws + (2u << 20));   // 4 MB
    int2*  bedges    = (int2*)(ws + (10u << 20));   // ~10 MB strided
    ushort_t* Tbf    = (ushort_t*)(ws + (20u << 20)); // 8 MB (2 x 4-MB planes)
    ushort_t* Ybf    = (ushort_t*)(ws + (28u << 20)); // 8 MB (2 x 4-MB planes)
    float* statsP    = (float*)(ws + (36u << 20));  // 4 MB (8192 x 128)

    // build
    hist_kernel<<<64, 256, 0, stream>>>((const int4*)src, partial, cursor, done);
    reduce_src<<<64, 256, 0, stream>>>(partial, (float4*)inv_so);
    bucket_scatter<<<256, 256, 0, stream>>>((const int4*)src, (const int4*)dst,
                                            (const float4*)ew, cursor, bedges);
    refine_lite<<<NBUCKET, 256, 0, stream>>>((const int*)bedges, cursor, nstart, ndeg);

    // layer 1
    gemm_f32<<<N_NODES / 64, 256, 0, stream>>>(x, W1, inv_so, Tbf);
    agg_bucket<<<NBUCKET, 1024, 0, stream>>>(Tbf, bedges, cursor, nstart, ndeg,
                                             Ybf, (float4*)statsP);
    reduce_finalize1<<<64, 256, 0, stream>>>(statsP, slab1, gn1_w, gn1_b, gn1_a,
                                             ab1 + 0, ab1 + 64, done + 0);

    // layer 2
    gemm_bf16<<<N_NODES / 64, 256, 0, stream>>>(Ybf, W2, inv_so, ab1 + 0, ab1 + 64, Tbf);
    agg_bucket<<<NBUCKET, 1024, 0, stream>>>(Tbf, bedges, cursor, nstart, ndeg,
                                             nullptr, (float4*)statsP);
    reduce_out2<<<96, 256, 0, stream>>>(statsP, slab2, pooledSum,
                                        gn2_w, gn2_b, gn2_a, Wc, (float*)d_out, done + 1);
}

// Round 14
// 162.167 us; speedup vs baseline: 1.0764x; 1.0764x over previous
//
#include <hip/hip_runtime.h>

#define N_NODES 65536
#define N_EDGES 1048576
#define B_GRAPHS 32
#define NPG     2048
#define EPS_GN  1e-5f
#define SLOPE   0.01f
#define NBUCKET 512     // buckets of 128 nodes (dst>>7)
#define STRIDE_B 2432   // fixed per-bucket capacity (mean 2048, sigma~45, ~8.5 sigma)

typedef unsigned short ushort_t;
typedef unsigned int uint_t;

static __device__ __forceinline__ ushort_t f2bf(float f) {
    uint_t u = __float_as_uint(f);
    return (ushort_t)((u + 0x7FFFu + ((u >> 16) & 1u)) >> 16);
}

static __device__ __forceinline__ void acc_bf8(float4& a0, float4& a1, uint4 u, float w) {
    a0.x += __uint_as_float(u.x << 16) * w;
    a0.y += __uint_as_float(u.x & 0xffff0000u) * w;
    a0.z += __uint_as_float(u.y << 16) * w;
    a0.w += __uint_as_float(u.y & 0xffff0000u) * w;
    a1.x += __uint_as_float(u.z << 16) * w;
    a1.y += __uint_as_float(u.z & 0xffff0000u) * w;
    a1.z += __uint_as_float(u.w << 16) * w;
    a1.w += __uint_as_float(u.w & 0xffff0000u) * w;
}

// ---------------- src histogram (byte-packed LDS bins); block 0 inits cursor+done ----
__global__ __launch_bounds__(256) void hist_kernel(const int4* __restrict__ src4,
                                                   unsigned int* __restrict__ partial,
                                                   int* __restrict__ cursor,
                                                   int* __restrict__ done) {
    __shared__ unsigned int bins[16384];   // 64 KB
    int tid = threadIdx.x, c = blockIdx.x;
#pragma unroll
    for (int k = 0; k < 64; ++k) bins[k * 256 + tid] = 0u;
    if (c == 0) {
        cursor[tid] = tid * STRIDE_B;
        cursor[256 + tid] = (256 + tid) * STRIDE_B;
        if (tid < 2) done[tid] = 0;
    }
    __syncthreads();
#pragma unroll
    for (int k = 0; k < 16; ++k) {
        int4 v = src4[c * 4096 + k * 256 + tid];
        atomicAdd(&bins[v.x >> 2], 1u << ((v.x & 3) * 8));
        atomicAdd(&bins[v.y >> 2], 1u << ((v.y & 3) * 8));
        atomicAdd(&bins[v.z >> 2], 1u << ((v.z & 3) * 8));
        atomicAdd(&bins[v.w >> 2], 1u << ((v.w & 3) * 8));
    }
    __syncthreads();
    unsigned int* dstp = partial + c * 16384;
#pragma unroll
    for (int k = 0; k < 64; ++k) dstp[k * 256 + tid] = bins[k * 256 + tid];
}

// ---------------- reduce byte-counters over 64 chunks -> inv_so ----------------
__global__ __launch_bounds__(256) void reduce_src(const unsigned int* __restrict__ partial,
                                                  float4* __restrict__ inv_so4) {
    int w = blockIdx.x * 256 + threadIdx.x;   // grid 64
    unsigned int s0 = 0, s1 = 0, s2 = 0, s3 = 0;
#pragma unroll
    for (int c = 0; c < 64; ++c) {
        unsigned int v = partial[c * 16384 + w];
        s0 += v & 255u; s1 += (v >> 8) & 255u; s2 += (v >> 16) & 255u; s3 += v >> 24;
    }
    float4 r;
    r.x = rsqrtf((float)max((int)s0, 1));
    r.y = rsqrtf((float)max((int)s1, 1));
    r.z = rsqrtf((float)max((int)s2, 1));
    r.w = rsqrtf((float)max((int)s3, 1));
    inv_so4[w] = r;
}

// ---------------- bucket scatter: 256 blocks x 4096-edge chunks, 512 fixed-stride buckets ----
__global__ __launch_bounds__(256) void bucket_scatter(const int4* __restrict__ src4,
                                                      const int4* __restrict__ dst4,
                                                      const float4* __restrict__ ew4,
                                                      int* __restrict__ cursor,
                                                      int2* __restrict__ bedges) {
    __shared__ int lhist[NBUCKET];
    __shared__ int lstart[NBUCKET];
    __shared__ int gbase[NBUCKET];
    __shared__ int scA[256], scB[256];
    __shared__ int2 staged[4096];   // 32 KB
    int tid = threadIdx.x;
    int vbase = blockIdx.x * 1024;  // 4096 edges = 1024 int4
    lhist[tid] = 0;
    lhist[tid + 256] = 0;
    __syncthreads();
    int w0[16]; int wbr[16]; float wwt[16];
#pragma unroll
    for (int k = 0; k < 4; ++k) {
        int4 s = src4[vbase + k * 256 + tid];
        int4 d = dst4[vbase + k * 256 + tid];
        float4 w = ew4[vbase + k * 256 + tid];
        int ss[4] = {s.x, s.y, s.z, s.w};
        int dd[4] = {d.x, d.y, d.z, d.w};
        float wf[4] = {w.x, w.y, w.z, w.w};
#pragma unroll
        for (int j = 0; j < 4; ++j) {
            int b = dd[j] >> 7;
            w0[k * 4 + j] = ss[j] | ((dd[j] & 127) << 16);
            wwt[k * 4 + j] = wf[j];
            int r = atomicAdd(&lhist[b], 1);
            wbr[k * 4 + j] = (b << 16) | r;
        }
    }
    __syncthreads();
    int cntA = lhist[tid], cntB = lhist[tid + 256];
    scA[tid] = cntA;
    scB[tid] = cntB;
    __syncthreads();
    for (int off = 1; off < 256; off <<= 1) {
        int tA = (tid >= off) ? scA[tid - off] : 0;
        int tB = (tid >= off) ? scB[tid - off] : 0;
        __syncthreads();
        scA[tid] += tA;
        scB[tid] += tB;
        __syncthreads();
    }
    int lowtot = scA[255];
    lstart[tid] = scA[tid] - cntA;
    lstart[tid + 256] = lowtot + scB[tid] - cntB;
    gbase[tid] = cntA ? atomicAdd(&cursor[tid], cntA) : 0;
    gbase[tid + 256] = cntB ? atomicAdd(&cursor[tid + 256], cntB) : 0;
    __syncthreads();
#pragma unroll
    for (int k = 0; k < 16; ++k)
        staged[lstart[wbr[k] >> 16] + (wbr[k] & 0xFFFF)] =
            make_int2(w0[k], __float_as_int(wwt[k]));
    __syncthreads();
    {
        int gb = gbase[tid], ls = lstart[tid];
        for (int i = 0; i < cntA; ++i) bedges[gb + i] = staged[ls + i];
        gb = gbase[tid + 256]; ls = lstart[tid + 256];
        for (int i = 0; i < cntB; ++i) bedges[gb + i] = staged[ls + i];
    }
}

// ---------------- refine_lite: per-bucket node histogram -> nstart/ndeg ----------------
__global__ __launch_bounds__(256) void refine_lite(const int* __restrict__ bedges_x,
                                                   const int* __restrict__ cursor,
                                                   int* __restrict__ nstart,
                                                   int* __restrict__ ndeg) {
    __shared__ int hist[128], sc[128];
    int tid = threadIdx.x, b = blockIdx.x;   // grid 512
    int e0 = b * STRIDE_B;
    int nE = cursor[b] - e0;
    if (tid < 128) hist[tid] = 0;
    __syncthreads();
    for (int i = tid; i < nE; i += 256)
        atomicAdd(&hist[(bedges_x[2 * (e0 + i)] >> 16) & 127], 1);
    __syncthreads();
    if (tid < 128) sc[tid] = hist[tid];
    __syncthreads();
    for (int off = 1; off < 128; off <<= 1) {
        int t = (tid >= off && tid < 128) ? sc[tid - off] : 0;
        __syncthreads();
        if (tid < 128) sc[tid] += t;
        __syncthreads();
    }
    if (tid < 128) {
        int cnt = hist[tid];
        nstart[b * 128 + tid] = sc[tid] - cnt;
        ndeg[b * 128 + tid] = cnt;
    }
}

// ---------------- gemm (fp32 input, layer 1), 64 rows/block ----------------
__global__ __launch_bounds__(256) void gemm_f32(const float* __restrict__ in,
                                                const float* __restrict__ W,
                                                const float* __restrict__ inv_so,
                                                ushort_t* __restrict__ out_bf) {
    __shared__ float wT[64][68];
    __shared__ float xlds[64][64];
    int tid = threadIdx.x;
#pragma unroll
    for (int j = 0; j < 16; ++j) {
        int i = j * 256 + tid;
        wT[i & 63][i >> 6] = W[i];
    }
    int r0 = blockIdx.x * 64;
#pragma unroll
    for (int j = 0; j < 16; ++j) {
        int i = j * 256 + tid;
        int r = i >> 6, k = i & 63;
        int gr = r0 + r;
        xlds[r][k] = in[(size_t)gr * 64 + k] * inv_so[gr];
    }
    __syncthreads();
    int c = tid & 63;
    int rg = tid >> 6;
    float acc[16];
#pragma unroll
    for (int j = 0; j < 16; ++j) acc[j] = 0.f;
#pragma unroll
    for (int k0 = 0; k0 < 64; k0 += 4) {
        float4 wv = *(const float4*)&wT[c][k0];
#pragma unroll
        for (int j = 0; j < 16; ++j) {
            float4 xv = *(const float4*)&xlds[rg * 16 + j][k0];
            acc[j] += xv.x * wv.x + xv.y * wv.y + xv.z * wv.z + xv.w * wv.w;
        }
    }
#pragma unroll
    for (int j = 0; j < 16; ++j)
        out_bf[(size_t)(r0 + rg * 16 + j) * 64 + c] = f2bf(acc[j]);
}

// ---------------- gemm (bf16 input, layer 2): GN1 affine fused, 64 rows/block ----------------
__global__ __launch_bounds__(256) void gemm_bf16(const ushort_t* __restrict__ in,
                                                 const float* __restrict__ W,
                                                 const float* __restrict__ inv_so,
                                                 const float* __restrict__ alpha,
                                                 const float* __restrict__ beta,
                                                 ushort_t* __restrict__ out_bf) {
    __shared__ float wT[64][68];
    __shared__ float xlds[64][64];
    int tid = threadIdx.x;
#pragma unroll
    for (int j = 0; j < 16; ++j) {
        int i = j * 256 + tid;
        wT[i & 63][i >> 6] = W[i];
    }
    int r0 = blockIdx.x * 64;
    const uint_t* inU = (const uint_t*)in;
#pragma unroll
    for (int j = 0; j < 8; ++j) {
        int idx = j * 256 + tid;            // 0..2047 = 64 rows x 32 uints
        int r = idx >> 5, kp = idx & 31;
        int gr = r0 + r;
        uint_t u = inU[(size_t)gr * 32 + kp];
        int k0 = kp * 2;
        float lo = __uint_as_float(u << 16);
        float hi = __uint_as_float(u & 0xffff0000u);
        float iso = inv_so[gr];
        xlds[r][k0]     = (alpha[k0] * lo + beta[k0]) * iso;
        xlds[r][k0 + 1] = (alpha[k0 + 1] * hi + beta[k0 + 1]) * iso;
    }
    __syncthreads();
    int c = tid & 63;
    int rg = tid >> 6;
    float acc[16];
#pragma unroll
    for (int j = 0; j < 16; ++j) acc[j] = 0.f;
#pragma unroll
    for (int k0 = 0; k0 < 64; k0 += 4) {
        float4 wv = *(const float4*)&wT[c][k0];
#pragma unroll
        for (int j = 0; j < 16; ++j) {
            float4 xv = *(const float4*)&xlds[rg * 16 + j][k0];
            acc[j] += xv.x * wv.x + xv.y * wv.y + xv.z * wv.z + xv.w * wv.w;
        }
    }
#pragma unroll
    for (int j = 0; j < 16; ++j)
        out_bf[(size_t)(r0 + rg * 16 + j) * 64 + c] = f2bf(acc[j]);
}

// ---------------- agg: 128-node bucket, single bedges pass, direct LDS sort, gather ----------
// grid 512, 1024 thr, ~21 KB LDS -> 2 blocks/CU
__global__ __launch_bounds__(1024, 8) void agg_bucket(const ushort_t* __restrict__ Tb,
                                                      const int2* __restrict__ bedges,
                                                      const int* __restrict__ cursor,
                                                      const int* __restrict__ nstart,
                                                      const int* __restrict__ ndeg,
                                                      ushort_t* __restrict__ Yb,   // nullable
                                                      float4* __restrict__ statsP4) {
    __shared__ int2 sorted[STRIDE_B];   // 19 KB
    __shared__ int nst[128], ndg[128], scur[128];
    int tid = threadIdx.x, b = blockIdx.x;
    int e0 = b * STRIDE_B;
    int nE = cursor[b] - e0;
    if (tid < 128) {
        int st = nstart[b * 128 + tid];
        nst[tid] = st;
        scur[tid] = st;
        ndg[tid] = ndeg[b * 128 + tid];
    }
    __syncthreads();
    for (int i = tid; i < nE; i += 1024) {
        int2 e = bedges[e0 + i];
        int dl = (e.x >> 16) & 127;
        int pos = atomicAdd(&scur[dl], 1);
        sorted[pos] = make_int2(e.x & 0xFFFF, e.y);
    }
    __syncthreads();
    const long* sl = (const long*)sorted;
    int l8 = tid & 7;
    int nl = tid >> 3;                 // 0..127
    int node = b * 128 + nl;
    int off = nst[nl];
    int cnt = ndg[nl];
    float4 a0 = make_float4(0.f, 0.f, 0.f, 0.f);
    float4 a1 = make_float4(0.f, 0.f, 0.f, 0.f);
    int i = 0;
    for (; i + 8 <= cnt; i += 8) {
        long e[8];
#pragma unroll
        for (int k = 0; k < 8; ++k) e[k] = sl[off + i + k];
        uint4 t[8];
#pragma unroll
        for (int k = 0; k < 8; ++k)
            t[k] = ((const uint4*)(Tb + (((size_t)(e[k] & 0xFFFF)) << 6)))[l8];
#pragma unroll
        for (int k = 0; k < 8; ++k)
            acc_bf8(a0, a1, t[k], __int_as_float((int)(e[k] >> 32)));
    }
    for (; i < cnt; ++i) {
        long e = sl[off + i];
        uint4 u = ((const uint4*)(Tb + (((size_t)(e & 0xFFFF)) << 6)))[l8];
        acc_bf8(a0, a1, u, __int_as_float((int)(e >> 32)));
    }
    float s = rsqrtf((float)max(cnt, 1));
    float4 v0, v1;
    v0.x = a0.x * s; v0.x = (v0.x >= 0.f) ? v0.x : SLOPE * v0.x;
    v0.y = a0.y * s; v0.y = (v0.y >= 0.f) ? v0.y : SLOPE * v0.y;
    v0.z = a0.z * s; v0.z = (v0.z >= 0.f) ? v0.z : SLOPE * v0.z;
    v0.w = a0.w * s; v0.w = (v0.w >= 0.f) ? v0.w : SLOPE * v0.w;
    v1.x = a1.x * s; v1.x = (v1.x >= 0.f) ? v1.x : SLOPE * v1.x;
    v1.y = a1.y * s; v1.y = (v1.y >= 0.f) ? v1.y : SLOPE * v1.y;
    v1.z = a1.z * s; v1.z = (v1.z >= 0.f) ? v1.z : SLOPE * v1.z;
    v1.w = a1.w * s; v1.w = (v1.w >= 0.f) ? v1.w : SLOPE * v1.w;
    if (Yb) {
        uint_t p0 = (uint_t)f2bf(v0.x) | ((uint_t)f2bf(v0.y) << 16);
        uint_t p1 = (uint_t)f2bf(v0.z) | ((uint_t)f2bf(v0.w) << 16);
        uint_t p2 = (uint_t)f2bf(v1.x) | ((uint_t)f2bf(v1.y) << 16);
        uint_t p3 = (uint_t)f2bf(v1.z) | ((uint_t)f2bf(v1.w) << 16);
        ((uint4*)Yb)[(size_t)node * 8 + l8] = make_uint4(p0, p1, p2, p3);
    }
    // per-wave stats partials via shfl (8 node-slots per wave)
    float4 s0 = v0, s1 = v1;
    float4 q0 = make_float4(v0.x * v0.x, v0.y * v0.y, v0.z * v0.z, v0.w * v0.w);
    float4 q1 = make_float4(v1.x * v1.x, v1.y * v1.y, v1.z * v1.z, v1.w * v1.w);
#pragma unroll
    for (int m = 8; m <= 32; m <<= 1) {
        s0.x += __shfl_xor(s0.x, m); s0.y += __shfl_xor(s0.y, m);
        s0.z += __shfl_xor(s0.z, m); s0.w += __shfl_xor(s0.w, m);
        s1.x += __shfl_xor(s1.x, m); s1.y += __shfl_xor(s1.y, m);
        s1.z += __shfl_xor(s1.z, m); s1.w += __shfl_xor(s1.w, m);
        q0.x += __shfl_xor(q0.x, m); q0.y += __shfl_xor(q0.y, m);
        q0.z += __shfl_xor(q0.z, m); q0.w += __shfl_xor(q0.w, m);
        q1.x += __shfl_xor(q1.x, m); q1.y += __shfl_xor(q1.y, m);
        q1.z += __shfl_xor(q1.z, m); q1.w += __shfl_xor(q1.w, m);
    }
    int wv = tid >> 6, ln = tid & 63;
    if (ln < 8) {
        float4* row = statsP4 + ((size_t)b * 16 + wv) * 32;
        row[ln * 2 + 0] = s0;
        row[ln * 2 + 1] = s1;
        row[16 + ln * 2 + 0] = q0;
        row[16 + ln * 2 + 1] = q1;
    }
}

// ---------------- reduce statsP -> slab; LAST block computes GN1 alpha/beta ----------------
__global__ __launch_bounds__(256) void reduce_finalize1(const float* __restrict__ statsP,
                                                        float* __restrict__ slab,
                                                        const float* __restrict__ w,
                                                        const float* __restrict__ bb,
                                                        const float* __restrict__ a,
                                                        float* __restrict__ alpha,
                                                        float* __restrict__ beta,
                                                        int* __restrict__ done) {
    __shared__ float red[256];
    __shared__ int isLast;
    int tid = threadIdx.x, b = blockIdx.x;   // grid 64
    int col = tid & 127, half = tid >> 7;
    float s = 0.f;
    for (int i = half; i < 128; i += 2)
        s += statsP[(size_t)(b * 128 + i) * 128 + col];
    red[tid] = s;
    __syncthreads();
    if (tid < 128) slab[b * 128 + tid] = red[tid] + red[tid + 128];
    __threadfence();
    if (tid == 0) isLast = (atomicAdd(done, 1) == 63);
    __syncthreads();
    if (isLast && tid < 64) {
        float Sy = 0.f, Qy = 0.f;
        for (int i = 0; i < 64; ++i) {
            Sy += slab[i * 128 + tid];
            Qy += slab[i * 128 + 64 + tid];
        }
        float m = Sy * (1.f / N_NODES);
        float q = Qy * (1.f / N_NODES);
        float af = a[tid];
        float var = q - 2.f * af * m * m + af * af * m * m;
        float al = w[tid] / sqrtf(var + EPS_GN);
        alpha[tid] = al;
        beta[tid] = bb[tid] - al * af * m;
    }
}

// ---------------- layer-2 reduce (stats + pool); LAST block does GN2 + pooled @ Wc^T ------
__global__ __launch_bounds__(256) void reduce_out2(const float* __restrict__ statsP,
                                                   float* __restrict__ slab,
                                                   float* __restrict__ pooledSum,
                                                   const float* __restrict__ gn_w,
                                                   const float* __restrict__ gn_b,
                                                   const float* __restrict__ gn_a,
                                                   const float* __restrict__ Wc,
                                                   float* __restrict__ out,
                                                   int* __restrict__ done) {
    __shared__ float red[256];
    __shared__ int isLast;
    int tid = threadIdx.x, b = blockIdx.x;   // grid 96
    if (b < 64) {
        int col = tid & 127, half = tid >> 7;
        float s = 0.f;
        for (int i = half; i < 128; i += 2)
            s += statsP[(size_t)(b * 128 + i) * 128 + col];
        red[tid] = s;
        __syncthreads();
        if (tid < 128) slab[b * 128 + tid] = red[tid] + red[tid + 128];
    } else {
        int g = b - 64;
        int col = tid & 63, part = tid >> 6;
        float s = 0.f;
        for (int r = g * 256 + part; r < (g + 1) * 256; r += 4)
            s += statsP[(size_t)r * 128 + col];
        red[tid] = s;
        __syncthreads();
        if (tid < 64)
            pooledSum[g * 64 + tid] =
                red[tid] + red[tid + 64] + red[tid + 128] + red[tid + 192];
    }
    __threadfence();
    if (tid == 0) isLast = (atomicAdd(done, 1) == 95);
    __syncthreads();
    if (!isLast) return;
    __shared__ float al[64], be[64];
    __shared__ float p[B_GRAPHS * 64];
    if (tid < 64) {
        float Sy = 0.f, Qy = 0.f;
        for (int i = 0; i < 64; ++i) {
            Sy += slab[i * 128 + tid];
            Qy += slab[i * 128 + 64 + tid];
        }
        float m = Sy * (1.f / N_NODES);
        float q = Qy * (1.f / N_NODES);
        float af = gn_a[tid];
        float var = q - 2.f * af * m * m + af * af * m * m;
        float a_ = gn_w[tid] / sqrtf(var + EPS_GN);
        al[tid] = a_;
        be[tid] = gn_b[tid] - a_ * af * m;
    }
    __syncthreads();
    for (int i = tid; i < B_GRAPHS * 64; i += 256) {
        int f = i & 63;
        p[i] = al[f] * (pooledSum[i] * (1.f / NPG)) + be[f];
    }
    __syncthreads();
    for (int idx = tid; idx < B_GRAPHS * 32; idx += 256) {
        int g = idx >> 5, o = idx & 31;
        float acc = 0.f;
        for (int f = 0; f < 64; ++f)
            acc += p[g * 64 + f] * Wc[o * 64 + f];
        out[idx] = acc;
    }
}

extern "C" void kernel_launch(void* const* d_in, const int* in_sizes, int n_in,
                              void* d_out, int out_size, void* d_ws, size_t ws_size,
                              hipStream_t stream) {
    const float* x     = (const float*)d_in[0];
    const float* ew    = (const float*)d_in[1];
    const float* W1    = (const float*)d_in[2];
    const float* W2    = (const float*)d_in[3];
    const float* Wc    = (const float*)d_in[4];
    const float* gn1_w = (const float*)d_in[5];
    const float* gn1_b = (const float*)d_in[6];
    const float* gn1_a = (const float*)d_in[7];
    const float* gn2_w = (const float*)d_in[8];
    const float* gn2_b = (const float*)d_in[9];
    const float* gn2_a = (const float*)d_in[10];
    const int* src     = (const int*)d_in[11];
    const int* dst     = (const int*)d_in[12];

    char* ws = (char*)d_ws;
    int*   cursor    = (int*)(ws + 0);              // 2 KB (512 ints)
    int*   done      = (int*)(ws + 2048);           // 2 ints
    float* ab1       = (float*)(ws + 4096);         // 512 B
    float* pooledSum = (float*)(ws + 8192);         // 8 KB
    float* slab1     = (float*)(ws + 16384);        // 32 KB
    float* slab2     = (float*)(ws + 49152);        // 32 KB
    int*   nstart    = (int*)(ws + 131072);         // 256 KB
    int*   ndeg      = (int*)(ws + 393216);         // 256 KB
    float* inv_so    = (float*)(ws + 655360);       // 256 KB
    unsigned int* partial = (unsigned int*)(ws + (2u << 20));   // 4 MB
    int2*  bedges    = (int2*)(ws + (10u << 20));   // ~10 MB strided
    ushort_t* Tbf    = (ushort_t*)(ws + (20u << 20)); // 8 MB
    ushort_t* Ybf    = (ushort_t*)(ws + (28u << 20)); // 8 MB
    float* statsP    = (float*)(ws + (36u << 20));  // 4 MB (8192 x 128)

    // build
    hist_kernel<<<64, 256, 0, stream>>>((const int4*)src, partial, cursor, done);
    reduce_src<<<64, 256, 0, stream>>>(partial, (float4*)inv_so);
    bucket_scatter<<<256, 256, 0, stream>>>((const int4*)src, (const int4*)dst,
                                            (const float4*)ew, cursor, bedges);
    refine_lite<<<NBUCKET, 256, 0, stream>>>((const int*)bedges, cursor, nstart, ndeg);

    // layer 1
    gemm_f32<<<N_NODES / 64, 256, 0, stream>>>(x, W1, inv_so, Tbf);
    agg_bucket<<<NBUCKET, 1024, 0, stream>>>(Tbf, bedges, cursor, nstart, ndeg,
                                             Ybf, (float4*)statsP);
    reduce_finalize1<<<64, 256, 0, stream>>>(statsP, slab1, gn1_w, gn1_b, gn1_a,
                                             ab1 + 0, ab1 + 64, done + 0);

    // layer 2
    gemm_bf16<<<N_NODES / 64, 256, 0, stream>>>(Ybf, W2, inv_so, ab1 + 0, ab1 + 64, Tbf);
    agg_bucket<<<NBUCKET, 1024, 0, stream>>>(Tbf, bedges, cursor, nstart, ndeg,
                                             nullptr, (float4*)statsP);
    reduce_out2<<<96, 256, 0, stream>>>(statsP, slab2, pooledSum,
                                        gn2_w, gn2_b, gn2_a, Wc, (float*)d_out, done + 1);
}

// Round 15
// 152.741 us; speedup vs baseline: 1.1428x; 1.0617x over previous
//
#include <hip/hip_runtime.h>

#define N_NODES 65536
#define N_EDGES 1048576
#define B_GRAPHS 32
#define NPG     2048
#define EPS_GN  1e-5f
#define SLOPE   0.01f
#define NBUCKET 512     // buckets of 128 nodes (dst>>7)
#define STRIDE_B 2432   // fixed per-bucket capacity (mean 2048, sigma~45, ~8.5 sigma)

typedef unsigned short ushort_t;
typedef unsigned int uint_t;

static __device__ __forceinline__ ushort_t f2bf(float f) {
    uint_t u = __float_as_uint(f);
    return (ushort_t)((u + 0x7FFFu + ((u >> 16) & 1u)) >> 16);
}

static __device__ __forceinline__ void acc_bf8(float4& a0, float4& a1, uint4 u, float w) {
    a0.x += __uint_as_float(u.x << 16) * w;
    a0.y += __uint_as_float(u.x & 0xffff0000u) * w;
    a0.z += __uint_as_float(u.y << 16) * w;
    a0.w += __uint_as_float(u.y & 0xffff0000u) * w;
    a1.x += __uint_as_float(u.z << 16) * w;
    a1.y += __uint_as_float(u.z & 0xffff0000u) * w;
    a1.z += __uint_as_float(u.w << 16) * w;
    a1.w += __uint_as_float(u.w & 0xffff0000u) * w;
}

// ---------------- src histogram (byte-packed LDS bins); block 0 inits cursor ----
__global__ __launch_bounds__(256) void hist_kernel(const int4* __restrict__ src4,
                                                   unsigned int* __restrict__ partial,
                                                   int* __restrict__ cursor) {
    __shared__ unsigned int bins[16384];   // 64 KB
    int tid = threadIdx.x, c = blockIdx.x;
#pragma unroll
    for (int k = 0; k < 64; ++k) bins[k * 256 + tid] = 0u;
    if (c == 0) {
        cursor[tid] = tid * STRIDE_B;
        cursor[256 + tid] = (256 + tid) * STRIDE_B;
    }
    __syncthreads();
#pragma unroll
    for (int k = 0; k < 16; ++k) {
        int4 v = src4[c * 4096 + k * 256 + tid];
        atomicAdd(&bins[v.x >> 2], 1u << ((v.x & 3) * 8));
        atomicAdd(&bins[v.y >> 2], 1u << ((v.y & 3) * 8));
        atomicAdd(&bins[v.z >> 2], 1u << ((v.z & 3) * 8));
        atomicAdd(&bins[v.w >> 2], 1u << ((v.w & 3) * 8));
    }
    __syncthreads();
    unsigned int* dstp = partial + c * 16384;
#pragma unroll
    for (int k = 0; k < 64; ++k) dstp[k * 256 + tid] = bins[k * 256 + tid];
}

// ---------------- reduce byte-counters over 64 chunks -> inv_so ----------------
__global__ __launch_bounds__(256) void reduce_src(const unsigned int* __restrict__ partial,
                                                  float4* __restrict__ inv_so4) {
    int w = blockIdx.x * 256 + threadIdx.x;   // grid 64
    unsigned int s0 = 0, s1 = 0, s2 = 0, s3 = 0;
#pragma unroll
    for (int c = 0; c < 64; ++c) {
        unsigned int v = partial[c * 16384 + w];
        s0 += v & 255u; s1 += (v >> 8) & 255u; s2 += (v >> 16) & 255u; s3 += v >> 24;
    }
    float4 r;
    r.x = rsqrtf((float)max((int)s0, 1));
    r.y = rsqrtf((float)max((int)s1, 1));
    r.z = rsqrtf((float)max((int)s2, 1));
    r.w = rsqrtf((float)max((int)s3, 1));
    inv_so4[w] = r;
}

// ---------------- bucket scatter: 256 blocks x 4096-edge chunks, 512 fixed-stride buckets ----
__global__ __launch_bounds__(256) void bucket_scatter(const int4* __restrict__ src4,
                                                      const int4* __restrict__ dst4,
                                                      const float4* __restrict__ ew4,
                                                      int* __restrict__ cursor,
                                                      int2* __restrict__ bedges) {
    __shared__ int lhist[NBUCKET];
    __shared__ int lstart[NBUCKET];
    __shared__ int gbase[NBUCKET];
    __shared__ int scA[256], scB[256];
    __shared__ int2 staged[4096];   // 32 KB
    int tid = threadIdx.x;
    int vbase = blockIdx.x * 1024;  // 4096 edges = 1024 int4
    lhist[tid] = 0;
    lhist[tid + 256] = 0;
    __syncthreads();
    int w0[16]; int wbr[16]; float wwt[16];
#pragma unroll
    for (int k = 0; k < 4; ++k) {
        int4 s = src4[vbase + k * 256 + tid];
        int4 d = dst4[vbase + k * 256 + tid];
        float4 w = ew4[vbase + k * 256 + tid];
        int ss[4] = {s.x, s.y, s.z, s.w};
        int dd[4] = {d.x, d.y, d.z, d.w};
        float wf[4] = {w.x, w.y, w.z, w.w};
#pragma unroll
        for (int j = 0; j < 4; ++j) {
            int b = dd[j] >> 7;
            w0[k * 4 + j] = ss[j] | ((dd[j] & 127) << 16);
            wwt[k * 4 + j] = wf[j];
            int r = atomicAdd(&lhist[b], 1);
            wbr[k * 4 + j] = (b << 16) | r;
        }
    }
    __syncthreads();
    int cntA = lhist[tid], cntB = lhist[tid + 256];
    scA[tid] = cntA;
    scB[tid] = cntB;
    __syncthreads();
    for (int off = 1; off < 256; off <<= 1) {
        int tA = (tid >= off) ? scA[tid - off] : 0;
        int tB = (tid >= off) ? scB[tid - off] : 0;
        __syncthreads();
        scA[tid] += tA;
        scB[tid] += tB;
        __syncthreads();
    }
    int lowtot = scA[255];
    lstart[tid] = scA[tid] - cntA;
    lstart[tid + 256] = lowtot + scB[tid] - cntB;
    gbase[tid] = cntA ? atomicAdd(&cursor[tid], cntA) : 0;
    gbase[tid + 256] = cntB ? atomicAdd(&cursor[tid + 256], cntB) : 0;
    __syncthreads();
#pragma unroll
    for (int k = 0; k < 16; ++k)
        staged[lstart[wbr[k] >> 16] + (wbr[k] & 0xFFFF)] =
            make_int2(w0[k], __float_as_int(wwt[k]));
    __syncthreads();
    {
        int gb = gbase[tid], ls = lstart[tid];
        for (int i = 0; i < cntA; ++i) bedges[gb + i] = staged[ls + i];
        gb = gbase[tid + 256]; ls = lstart[tid + 256];
        for (int i = 0; i < cntB; ++i) bedges[gb + i] = staged[ls + i];
    }
}

// ---------------- gemm (fp32 input, layer 1), 64 rows/block ----------------
__global__ __launch_bounds__(256) void gemm_f32(const float* __restrict__ in,
                                                const float* __restrict__ W,
                                                const float* __restrict__ inv_so,
                                                ushort_t* __restrict__ out_bf) {
    __shared__ float wT[64][68];
    __shared__ float xlds[64][64];
    int tid = threadIdx.x;
#pragma unroll
    for (int j = 0; j < 16; ++j) {
        int i = j * 256 + tid;
        wT[i & 63][i >> 6] = W[i];
    }
    int r0 = blockIdx.x * 64;
#pragma unroll
    for (int j = 0; j < 16; ++j) {
        int i = j * 256 + tid;
        int r = i >> 6, k = i & 63;
        int gr = r0 + r;
        xlds[r][k] = in[(size_t)gr * 64 + k] * inv_so[gr];
    }
    __syncthreads();
    int c = tid & 63;
    int rg = tid >> 6;
    float acc[16];
#pragma unroll
    for (int j = 0; j < 16; ++j) acc[j] = 0.f;
#pragma unroll
    for (int k0 = 0; k0 < 64; k0 += 4) {
        float4 wv = *(const float4*)&wT[c][k0];
#pragma unroll
        for (int j = 0; j < 16; ++j) {
            float4 xv = *(const float4*)&xlds[rg * 16 + j][k0];
            acc[j] += xv.x * wv.x + xv.y * wv.y + xv.z * wv.z + xv.w * wv.w;
        }
    }
#pragma unroll
    for (int j = 0; j < 16; ++j)
        out_bf[(size_t)(r0 + rg * 16 + j) * 64 + c] = f2bf(acc[j]);
}

// ---------------- gemm (bf16 input, layer 2): GN1 affine fused, 64 rows/block ----------------
__global__ __launch_bounds__(256) void gemm_bf16(const ushort_t* __restrict__ in,
                                                 const float* __restrict__ W,
                                                 const float* __restrict__ inv_so,
                                                 const float* __restrict__ alpha,
                                                 const float* __restrict__ beta,
                                                 ushort_t* __restrict__ out_bf) {
    __shared__ float wT[64][68];
    __shared__ float xlds[64][64];
    int tid = threadIdx.x;
#pragma unroll
    for (int j = 0; j < 16; ++j) {
        int i = j * 256 + tid;
        wT[i & 63][i >> 6] = W[i];
    }
    int r0 = blockIdx.x * 64;
    const uint_t* inU = (const uint_t*)in;
#pragma unroll
    for (int j = 0; j < 8; ++j) {
        int idx = j * 256 + tid;            // 0..2047 = 64 rows x 32 uints
        int r = idx >> 5, kp = idx & 31;
        int gr = r0 + r;
        uint_t u = inU[(size_t)gr * 32 + kp];
        int k0 = kp * 2;
        float lo = __uint_as_float(u << 16);
        float hi = __uint_as_float(u & 0xffff0000u);
        float iso = inv_so[gr];
        xlds[r][k0]     = (alpha[k0] * lo + beta[k0]) * iso;
        xlds[r][k0 + 1] = (alpha[k0 + 1] * hi + beta[k0 + 1]) * iso;
    }
    __syncthreads();
    int c = tid & 63;
    int rg = tid >> 6;
    float acc[16];
#pragma unroll
    for (int j = 0; j < 16; ++j) acc[j] = 0.f;
#pragma unroll
    for (int k0 = 0; k0 < 64; k0 += 4) {
        float4 wv = *(const float4*)&wT[c][k0];
#pragma unroll
        for (int j = 0; j < 16; ++j) {
            float4 xv = *(const float4*)&xlds[rg * 16 + j][k0];
            acc[j] += xv.x * wv.x + xv.y * wv.y + xv.z * wv.z + xv.w * wv.w;
        }
    }
#pragma unroll
    for (int j = 0; j < 16; ++j)
        out_bf[(size_t)(r0 + rg * 16 + j) * 64 + c] = f2bf(acc[j]);
}

// ---------------- agg: fused in-LDS hist/scan/sort + gather (refine_lite folded in) ----------
// grid 512, 1024 thr, ~41 KB LDS -> 2 blocks/CU (thread-limited)
__global__ __launch_bounds__(1024, 8) void agg_bucket(const ushort_t* __restrict__ Tb,
                                                      const int2* __restrict__ bedges,
                                                      const int* __restrict__ cursor,
                                                      ushort_t* __restrict__ Yb,   // nullable
                                                      float4* __restrict__ statsP4) {
    __shared__ int2 staged[STRIDE_B];   // 19 KB
    __shared__ int2 sorted[STRIDE_B];   // 19 KB
    __shared__ int hist[128], sc[128], nst[128], scur[128];
    int tid = threadIdx.x, b = blockIdx.x;
    int e0 = b * STRIDE_B;
    int nE = cursor[b] - e0;
    if (tid < 128) hist[tid] = 0;
    __syncthreads();
    for (int i = tid; i < nE; i += 1024) {
        int2 e = bedges[e0 + i];
        staged[i] = e;
        atomicAdd(&hist[(e.x >> 16) & 127], 1);
    }
    __syncthreads();
    if (tid < 128) sc[tid] = hist[tid];
    __syncthreads();
    for (int off = 1; off < 128; off <<= 1) {
        int t = (tid >= off && tid < 128) ? sc[tid - off] : 0;
        __syncthreads();
        if (tid < 128) sc[tid] += t;
        __syncthreads();
    }
    if (tid < 128) {
        int start = sc[tid] - hist[tid];
        nst[tid] = start;
        scur[tid] = start;
    }
    __syncthreads();
    for (int i = tid; i < nE; i += 1024) {
        int2 e = staged[i];
        int pos = atomicAdd(&scur[(e.x >> 16) & 127], 1);
        sorted[pos] = make_int2(e.x & 0xFFFF, e.y);   // src fits 16 bits
    }
    __syncthreads();
    const long* sl = (const long*)sorted;
    int l8 = tid & 7;
    int nl = tid >> 3;                 // 0..127
    int node = b * 128 + nl;
    int off = nst[nl];
    int cnt = hist[nl];
    float4 a0 = make_float4(0.f, 0.f, 0.f, 0.f);
    float4 a1 = make_float4(0.f, 0.f, 0.f, 0.f);
    int i = 0;
    for (; i + 8 <= cnt; i += 8) {
        long e[8];
#pragma unroll
        for (int k = 0; k < 8; ++k) e[k] = sl[off + i + k];
        uint4 t[8];
#pragma unroll
        for (int k = 0; k < 8; ++k)
            t[k] = ((const uint4*)(Tb + (((size_t)(e[k] & 0xFFFF)) << 6)))[l8];
#pragma unroll
        for (int k = 0; k < 8; ++k)
            acc_bf8(a0, a1, t[k], __int_as_float((int)(e[k] >> 32)));
    }
    for (; i < cnt; ++i) {
        long e = sl[off + i];
        uint4 u = ((const uint4*)(Tb + (((size_t)(e & 0xFFFF)) << 6)))[l8];
        acc_bf8(a0, a1, u, __int_as_float((int)(e >> 32)));
    }
    float s = rsqrtf((float)max(cnt, 1));
    float4 v0, v1;
    v0.x = a0.x * s; v0.x = (v0.x >= 0.f) ? v0.x : SLOPE * v0.x;
    v0.y = a0.y * s; v0.y = (v0.y >= 0.f) ? v0.y : SLOPE * v0.y;
    v0.z = a0.z * s; v0.z = (v0.z >= 0.f) ? v0.z : SLOPE * v0.z;
    v0.w = a0.w * s; v0.w = (v0.w >= 0.f) ? v0.w : SLOPE * v0.w;
    v1.x = a1.x * s; v1.x = (v1.x >= 0.f) ? v1.x : SLOPE * v1.x;
    v1.y = a1.y * s; v1.y = (v1.y >= 0.f) ? v1.y : SLOPE * v1.y;
    v1.z = a1.z * s; v1.z = (v1.z >= 0.f) ? v1.z : SLOPE * v1.z;
    v1.w = a1.w * s; v1.w = (v1.w >= 0.f) ? v1.w : SLOPE * v1.w;
    if (Yb) {
        uint_t p0 = (uint_t)f2bf(v0.x) | ((uint_t)f2bf(v0.y) << 16);
        uint_t p1 = (uint_t)f2bf(v0.z) | ((uint_t)f2bf(v0.w) << 16);
        uint_t p2 = (uint_t)f2bf(v1.x) | ((uint_t)f2bf(v1.y) << 16);
        uint_t p3 = (uint_t)f2bf(v1.z) | ((uint_t)f2bf(v1.w) << 16);
        ((uint4*)Yb)[(size_t)node * 8 + l8] = make_uint4(p0, p1, p2, p3);
    }
    // per-wave stats partials via shfl (8 node-slots per wave)
    float4 s0 = v0, s1 = v1;
    float4 q0 = make_float4(v0.x * v0.x, v0.y * v0.y, v0.z * v0.z, v0.w * v0.w);
    float4 q1 = make_float4(v1.x * v1.x, v1.y * v1.y, v1.z * v1.z, v1.w * v1.w);
#pragma unroll
    for (int m = 8; m <= 32; m <<= 1) {
        s0.x += __shfl_xor(s0.x, m); s0.y += __shfl_xor(s0.y, m);
        s0.z += __shfl_xor(s0.z, m); s0.w += __shfl_xor(s0.w, m);
        s1.x += __shfl_xor(s1.x, m); s1.y += __shfl_xor(s1.y, m);
        s1.z += __shfl_xor(s1.z, m); s1.w += __shfl_xor(s1.w, m);
        q0.x += __shfl_xor(q0.x, m); q0.y += __shfl_xor(q0.y, m);
        q0.z += __shfl_xor(q0.z, m); q0.w += __shfl_xor(q0.w, m);
        q1.x += __shfl_xor(q1.x, m); q1.y += __shfl_xor(q1.y, m);
        q1.z += __shfl_xor(q1.z, m); q1.w += __shfl_xor(q1.w, m);
    }
    int wv = tid >> 6, ln = tid & 63;
    if (ln < 8) {
        float4* row = statsP4 + ((size_t)b * 16 + wv) * 32;
        row[ln * 2 + 0] = s0;
        row[ln * 2 + 1] = s1;
        row[16 + ln * 2 + 0] = q0;
        row[16 + ln * 2 + 1] = q1;
    }
}

// ---------------- stage A: 8192x128 partials -> slab[64][128] ----------------
__global__ __launch_bounds__(256) void reduce_statsA(const float* __restrict__ statsP,
                                                     float* __restrict__ slab) {
    __shared__ float red[256];
    int tid = threadIdx.x, b = blockIdx.x;   // grid 64
    int col = tid & 127, half = tid >> 7;
    float s = 0.f;
    for (int i = half; i < 128; i += 2)
        s += statsP[(size_t)(b * 128 + i) * 128 + col];
    red[tid] = s;
    __syncthreads();
    if (tid < 128) slab[b * 128 + tid] = red[tid] + red[tid + 128];
}

// ---------------- merged layer-2 reduce: blocks 0-63 statsA, blocks 64-95 pool ----------------
__global__ __launch_bounds__(256) void reduce_stats2(const float* __restrict__ statsP,
                                                     float* __restrict__ slab,
                                                     float* __restrict__ pooledSum) {
    __shared__ float red[256];
    int tid = threadIdx.x, b = blockIdx.x;
    if (b < 64) {
        int col = tid & 127, half = tid >> 7;
        float s = 0.f;
        for (int i = half; i < 128; i += 2)
            s += statsP[(size_t)(b * 128 + i) * 128 + col];
        red[tid] = s;
        __syncthreads();
        if (tid < 128) slab[b * 128 + tid] = red[tid] + red[tid + 128];
    } else {
        int g = b - 64;
        int col = tid & 63, part = tid >> 6;
        float s = 0.f;
        for (int r = g * 256 + part; r < (g + 1) * 256; r += 4)
            s += statsP[(size_t)r * 128 + col];
        red[tid] = s;
        __syncthreads();
        if (tid < 64)
            pooledSum[g * 64 + tid] =
                red[tid] + red[tid + 64] + red[tid + 128] + red[tid + 192];
    }
}

// ---------------- finalize layer-1 GN: slab -> alpha/beta ----------------
__global__ void finalize_kernel(const float* __restrict__ slab,
                                const float* __restrict__ w, const float* __restrict__ b,
                                const float* __restrict__ a,
                                float* __restrict__ alpha, float* __restrict__ beta) {
    int f = threadIdx.x;   // 64 threads
    float Sy = 0.f, Qy = 0.f;
    for (int i = 0; i < 64; ++i) {
        Sy += slab[i * 128 + f];
        Qy += slab[i * 128 + 64 + f];
    }
    float m = Sy * (1.f / N_NODES);
    float q = Qy * (1.f / N_NODES);
    float af = a[f];
    float var = q - 2.f * af * m * m + af * af * m * m;
    float al = w[f] / sqrtf(var + EPS_GN);
    alpha[f] = al;
    beta[f] = b[f] - al * af * m;
}

// ---------------- out: GN2 finalize + pooled affine + @ Wc^T ----------------
__global__ __launch_bounds__(256) void out_kernel(const float* __restrict__ slab2,
                                                  const float* __restrict__ gn_w,
                                                  const float* __restrict__ gn_b,
                                                  const float* __restrict__ gn_a,
                                                  const float* __restrict__ pooledSum,
                                                  const float* __restrict__ Wc,
                                                  float* __restrict__ out) {
    __shared__ float al[64], be[64];
    __shared__ float p[B_GRAPHS * 64];
    int tid = threadIdx.x;
    if (tid < 64) {
        float Sy = 0.f, Qy = 0.f;
        for (int i = 0; i < 64; ++i) {
            Sy += slab2[i * 128 + tid];
            Qy += slab2[i * 128 + 64 + tid];
        }
        float m = Sy * (1.f / N_NODES);
        float q = Qy * (1.f / N_NODES);
        float af = gn_a[tid];
        float var = q - 2.f * af * m * m + af * af * m * m;
        float a_ = gn_w[tid] / sqrtf(var + EPS_GN);
        al[tid] = a_;
        be[tid] = gn_b[tid] - a_ * af * m;
    }
    __syncthreads();
    for (int i = tid; i < B_GRAPHS * 64; i += 256) {
        int f = i & 63;
        p[i] = al[f] * (pooledSum[i] * (1.f / NPG)) + be[f];
    }
    __syncthreads();
    for (int idx = tid; idx < B_GRAPHS * 32; idx += 256) {
        int g = idx >> 5, o = idx & 31;
        float acc = 0.f;
        for (int f = 0; f < 64; ++f)
            acc += p[g * 64 + f] * Wc[o * 64 + f];
        out[idx] = acc;
    }
}

extern "C" void kernel_launch(void* const* d_in, const int* in_sizes, int n_in,
                              void* d_out, int out_size, void* d_ws, size_t ws_size,
                              hipStream_t stream) {
    const float* x     = (const float*)d_in[0];
    const float* ew    = (const float*)d_in[1];
    const float* W1    = (const float*)d_in[2];
    const float* W2    = (const float*)d_in[3];
    const float* Wc    = (const float*)d_in[4];
    const float* gn1_w = (const float*)d_in[5];
    const float* gn1_b = (const float*)d_in[6];
    const float* gn1_a = (const float*)d_in[7];
    const float* gn2_w = (const float*)d_in[8];
    const float* gn2_b = (const float*)d_in[9];
    const float* gn2_a = (const float*)d_in[10];
    const int* src     = (const int*)d_in[11];
    const int* dst     = (const int*)d_in[12];

    char* ws = (char*)d_ws;
    int*   cursor    = (int*)(ws + 0);              // 2 KB (512 ints)
    float* ab1       = (float*)(ws + 4096);         // 512 B
    float* pooledSum = (float*)(ws + 8192);         // 8 KB
    float* slab1     = (float*)(ws + 16384);        // 32 KB
    float* slab2     = (float*)(ws + 49152);        // 32 KB
    float* inv_so    = (float*)(ws + 655360);       // 256 KB
    unsigned int* partial = (unsigned int*)(ws + (2u << 20));   // 4 MB
    int2*  bedges    = (int2*)(ws + (10u << 20));   // ~10 MB strided
    ushort_t* Tbf    = (ushort_t*)(ws + (20u << 20)); // 8 MB
    ushort_t* Ybf    = (ushort_t*)(ws + (28u << 20)); // 8 MB
    float* statsP    = (float*)(ws + (36u << 20));  // 4 MB (8192 x 128)

    // build
    hist_kernel<<<64, 256, 0, stream>>>((const int4*)src, partial, cursor);
    reduce_src<<<64, 256, 0, stream>>>(partial, (float4*)inv_so);
    bucket_scatter<<<256, 256, 0, stream>>>((const int4*)src, (const int4*)dst,
                                            (const float4*)ew, cursor, bedges);

    // layer 1
    gemm_f32<<<N_NODES / 64, 256, 0, stream>>>(x, W1, inv_so, Tbf);
    agg_bucket<<<NBUCKET, 1024, 0, stream>>>(Tbf, bedges, cursor, Ybf, (float4*)statsP);
    reduce_statsA<<<64, 256, 0, stream>>>(statsP, slab1);
    finalize_kernel<<<1, 64, 0, stream>>>(slab1, gn1_w, gn1_b, gn1_a, ab1 + 0, ab1 + 64);

    // layer 2
    gemm_bf16<<<N_NODES / 64, 256, 0, stream>>>(Ybf, W2, inv_so, ab1 + 0, ab1 + 64, Tbf);
    agg_bucket<<<NBUCKET, 1024, 0, stream>>>(Tbf, bedges, cursor, nullptr, (float4*)statsP);
    reduce_stats2<<<96, 256, 0, stream>>>(statsP, slab2, pooledSum);

    // GN2 finalize + pooled affine + classifier
    out_kernel<<<1, 256, 0, stream>>>(slab2, gn2_w, gn2_b, gn2_a, pooledSum, Wc,
                                      (float*)d_out);
}